// Round 1
// baseline (345.377 us; speedup 1.0000x reference)
//
#include <hip/hip_runtime.h>
#include <cfloat>

// TopKPooling: per (b, d) channel, top-8 over L with monotone padding mask.
// x: (B=32, L=8192, D=256) f32, x_mask: (B, L) i32 (1 = padded, monotone 0->1)
// out: (B, 8*D) f32, out[b][k*D + d] = k-th largest of valid x[b][:,d].
//
// Strategy: memory-bound. Pass 1 tiles L into NCHUNK chunks; each block
// (b, chunk) has thread d scanning its column slice with a branchless
// 8-register sorted-insert (15 VALU ops/elem). Monotone mask => fully-masked
// chunks are skipped without reading x (halves HBM traffic on average);
// the single mixed chunk per row binary-searches the boundary. Partial
// sorted top-8 lists land in ws; pass 2 merges 32 lists -> 8 via a 4-way
// split + LDS reduction.

#define TOPK 8
#define BB 32
#define LL 8192
#define DD 256

__device__ __forceinline__ void insert8(float r[TOPK], float v) {
    // r sorted descending. New multiset = {r0..r6} U {max(r7, v)}; one
    // bubble pass re-sorts. Fully branchless: 1 max + 7 compare-exchanges.
    r[7] = fmaxf(r[7], v);
#pragma unroll
    for (int j = TOPK - 1; j > 0; --j) {
        float hi = fmaxf(r[j - 1], r[j]);
        float lo = fminf(r[j - 1], r[j]);
        r[j - 1] = hi;
        r[j] = lo;
    }
}

__global__ __launch_bounds__(256, 4) void topk_pass1(
    const float* __restrict__ x, const int* __restrict__ mask,
    float* __restrict__ ws, int nchunk, int cl) {
    const int b = blockIdx.x;
    const int chunk = blockIdx.y;
    const int d = threadIdx.x;
    const int l0 = chunk * cl;
    const int* mrow = mask + b * LL;

    // Chunk-level mask classification (mask is monotone non-decreasing).
    const int mfirst = mrow[l0];
    const int mlast = mrow[l0 + cl - 1];

    int nvalid;
    if (mfirst) {
        nvalid = 0;                       // fully padded: skip all x reads
    } else if (!mlast) {
        nvalid = cl;                      // fully valid: no per-elem mask
    } else {
        // mixed chunk (exactly one per row): binary-search first padded pos
        int lo = l0 + 1, hi = l0 + cl - 1;   // mrow[l0]==0, mrow[hi]==1
        while (lo < hi) {
            int mid = (lo + hi) >> 1;
            if (mrow[mid]) hi = mid; else lo = mid + 1;
        }
        nvalid = lo - l0;
    }

    float r[TOPK];
#pragma unroll
    for (int k = 0; k < TOPK; ++k) r[k] = -FLT_MAX;

    const float* xp = x + ((size_t)b * LL + l0) * DD + d;
    int l = 0;
    // 4-wide batched loads so the compiler keeps 4 vmem ops in flight
    for (; l + 4 <= nvalid; l += 4) {
        float v0 = xp[(size_t)(l + 0) * DD];
        float v1 = xp[(size_t)(l + 1) * DD];
        float v2 = xp[(size_t)(l + 2) * DD];
        float v3 = xp[(size_t)(l + 3) * DD];
        insert8(r, v0);
        insert8(r, v1);
        insert8(r, v2);
        insert8(r, v3);
    }
    for (; l < nvalid; ++l) insert8(r, xp[(size_t)l * DD]);

    // ws layout: [b][chunk][k][d] -> coalesced writes here, coalesced reads
    // in pass 2. Every slot is written (skip-chunks write -FLT_MAX) since
    // the harness poisons ws before each timed call.
    float* wp = ws + ((size_t)(b * nchunk + chunk) * TOPK) * DD + d;
#pragma unroll
    for (int k = 0; k < TOPK; ++k) wp[(size_t)k * DD] = r[k];
}

__global__ __launch_bounds__(256, 4) void topk_pass2(
    const float* __restrict__ ws, float* __restrict__ out, int P) {
    // grid (B, 4): block handles 64 channels; 4 thread-groups (ps) each
    // merge P/4 sorted lists, then ps==0 folds the 4 results via LDS.
    __shared__ float lds[4 * TOPK * 64];   // [ps*8+k][c] -> conflict-free
    const int b = blockIdx.x;
    const int q = blockIdx.y;
    const int c = threadIdx.x & 63;
    const int ps = threadIdx.x >> 6;       // 0..3
    const int d = q * 64 + c;
    const int lists = P >> 2;

    float r[TOPK];
#pragma unroll
    for (int k = 0; k < TOPK; ++k) r[k] = -FLT_MAX;

    const float* wp = ws + ((size_t)b * P + (size_t)ps * lists) * TOPK * DD + d;
    for (int j = 0; j < lists; ++j) {
#pragma unroll
        for (int k = 0; k < TOPK; ++k) {
            insert8(r, wp[((size_t)j * TOPK + k) * DD]);
        }
    }

#pragma unroll
    for (int k = 0; k < TOPK; ++k) lds[(ps * TOPK + k) * 64 + c] = r[k];
    __syncthreads();

    if (ps == 0) {
#pragma unroll
        for (int p2 = 1; p2 < 4; ++p2) {
#pragma unroll
            for (int k = 0; k < TOPK; ++k) {
                insert8(r, lds[(p2 * TOPK + k) * 64 + c]);
            }
        }
        float* op = out + (size_t)b * (TOPK * DD) + d;
#pragma unroll
        for (int k = 0; k < TOPK; ++k) op[(size_t)k * DD] = r[k];
    }
}

// Fallback if ws is too small for even 4 chunks: one thread per (b, d)
// scans the full column. Slow but correct, needs no workspace.
__global__ __launch_bounds__(256) void topk_fallback(
    const float* __restrict__ x, const int* __restrict__ mask,
    float* __restrict__ out) {
    const int b = blockIdx.x;
    const int d = threadIdx.x;
    const int* mrow = mask + b * LL;
    int lo = 0, hi = LL;
    while (lo < hi) {
        int mid = (lo + hi) >> 1;
        if (mrow[mid]) hi = mid; else lo = mid + 1;
    }
    const int len = lo;

    float r[TOPK];
#pragma unroll
    for (int k = 0; k < TOPK; ++k) r[k] = -FLT_MAX;

    const float* xp = x + (size_t)b * LL * DD + d;
    int l = 0;
    for (; l + 4 <= len; l += 4) {
        float v0 = xp[(size_t)(l + 0) * DD];
        float v1 = xp[(size_t)(l + 1) * DD];
        float v2 = xp[(size_t)(l + 2) * DD];
        float v3 = xp[(size_t)(l + 3) * DD];
        insert8(r, v0);
        insert8(r, v1);
        insert8(r, v2);
        insert8(r, v3);
    }
    for (; l < len; ++l) insert8(r, xp[(size_t)l * DD]);

    float* op = out + (size_t)b * (TOPK * DD) + d;
#pragma unroll
    for (int k = 0; k < TOPK; ++k) op[(size_t)k * DD] = r[k];
}

extern "C" void kernel_launch(void* const* d_in, const int* in_sizes, int n_in,
                              void* d_out, int out_size, void* d_ws, size_t ws_size,
                              hipStream_t stream) {
    const float* x = (const float*)d_in[0];
    const int* mask = (const int*)d_in[1];
    float* out = (float*)d_out;

    // Choose chunk count by workspace budget (ws_size is fixed across calls,
    // so this branch is deterministic). Need B*nchunk*8*D*4 bytes.
    int nchunk = 32;
    while (nchunk > 2 && (size_t)BB * nchunk * TOPK * DD * 4 > ws_size) nchunk >>= 1;

    if (nchunk >= 4) {
        float* ws = (float*)d_ws;
        dim3 g1(BB, nchunk);
        topk_pass1<<<g1, 256, 0, stream>>>(x, mask, ws, nchunk, LL / nchunk);
        dim3 g2(BB, 4);
        topk_pass2<<<g2, 256, 0, stream>>>(ws, out, nchunk);
    } else {
        topk_fallback<<<BB, 256, 0, stream>>>(x, mask, out);
    }
}